// Round 1
// baseline (611.696 us; speedup 1.0000x reference)
//
#include <hip/hip_runtime.h>
#include <hip/hip_bf16.h>
#include <math.h>

// Problem constants (fixed by setup_inputs)
#define DM 1024          // d_model
#define NS 16            // d_state
#define BSZ 8
#define LSEQ 1024
#define MROWS (BSZ*LSEQ) // 8192 token rows

typedef __bf16 bf16;
typedef bf16 bf16x8 __attribute__((ext_vector_type(8)));
typedef bf16 bf16x4 __attribute__((ext_vector_type(4)));
typedef float f32x4 __attribute__((ext_vector_type(4)));

__device__ __forceinline__ void async16(const void* g, void* l) {
  __builtin_amdgcn_global_load_lds((const __attribute__((address_space(1))) void*)g,
                                   (__attribute__((address_space(3))) void*)l,
                                   16, 0, 0);
}

// ---------------------------------------------------------------------------
// f32 -> bf16 cast (weights)
// ---------------------------------------------------------------------------
__global__ void cast_f2b(const float* __restrict__ s, bf16* __restrict__ d, int n4) {
  int i = blockIdx.x * 256 + threadIdx.x;
  if (i < n4) {
    float4 v = ((const float4*)s)[i];
    bf16x4 o;
    o.x = (bf16)v.x; o.y = (bf16)v.y; o.z = (bf16)v.z; o.w = (bf16)v.w;
    *(bf16x4*)(d + 4 * (size_t)i) = o;
  }
}

// ---------------------------------------------------------------------------
// LayerNorm over d=1024, writes bf16 x_norm. One block (256 thr) per row.
// ---------------------------------------------------------------------------
__global__ void ln_kernel(const float* __restrict__ x, const float* __restrict__ g,
                          const float* __restrict__ b, bf16* __restrict__ out) {
  const size_t row = blockIdx.x;
  const int t = threadIdx.x;
  float4 v = ((const float4*)(x + row * DM))[t];
  float s = v.x + v.y + v.z + v.w;
  float s2 = v.x*v.x + v.y*v.y + v.z*v.z + v.w*v.w;
#pragma unroll
  for (int m = 1; m < 64; m <<= 1) { s += __shfl_xor(s, m, 64); s2 += __shfl_xor(s2, m, 64); }
  __shared__ float red[8];
  int wave = t >> 6, lane = t & 63;
  if (lane == 0) { red[wave] = s; red[4 + wave] = s2; }
  __syncthreads();
  s  = red[0] + red[1] + red[2] + red[3];
  s2 = red[4] + red[5] + red[6] + red[7];
  float mu  = s * (1.f / DM);
  float var = s2 * (1.f / DM) - mu * mu;
  float inv = rsqrtf(var + 1e-5f);
  float4 gg = ((const float4*)g)[t];
  float4 bb = ((const float4*)b)[t];
  bf16x4 o;
  o.x = (bf16)((v.x - mu) * inv * gg.x + bb.x);
  o.y = (bf16)((v.y - mu) * inv * gg.y + bb.y);
  o.z = (bf16)((v.z - mu) * inv * gg.z + bb.z);
  o.w = (bf16)((v.w - mu) * inv * gg.w + bb.w);
  *(bf16x4*)(out + row * DM + t * 4) = o;
}

// ---------------------------------------------------------------------------
// MFMA bf16 GEMM: C[M,N] = A[M,K] @ W[N,K]^T  (m97 structure: 128x128 tile,
// BK=32, 4 waves -> 2x2 grid of 64x64 wave tiles, 4x4 MFMA 16x16x32 per wave,
// global_load_lds width=16 staging).
// EPI 0: split into x_in(f32 + bf16) [n<1024] and z(f32) [n>=1024]
// EPI 1: dt = softplus(acc + b_dt[n])
// EPI 2: out = acc + residual[m*DM+n]
// ---------------------------------------------------------------------------
template <int EPI>
__global__ __launch_bounds__(256)
void gemm_bf16(const bf16* __restrict__ A, const bf16* __restrict__ W, int K,
               float* __restrict__ out_f, bf16* __restrict__ out_b,
               float* __restrict__ out_f2, const float* __restrict__ aux) {
  __shared__ bf16 As[128 * 32];
  __shared__ bf16 Bs[128 * 32];
  const int tid  = threadIdx.x;
  const int wave = tid >> 6, lane = tid & 63;
  const int lr = lane & 15, quad = lane >> 4;
  const size_t arow = (size_t)blockIdx.y * 128;
  const size_t brow = (size_t)blockIdx.x * 128;
  f32x4 acc[4][4] = {};

  // staging addresses: each wave stages rows [wave*32, wave*32+32) of each tile
  const int srow = wave * 32 + (lane >> 2);
  const int skc  = (lane & 3) * 8;
  const bf16* ag = A + (arow + srow) * (size_t)K + skc;
  const bf16* wg = W + (brow + srow) * (size_t)K + skc;
  bf16* asl = &As[wave * 32 * 32];
  bf16* bsl = &Bs[wave * 32 * 32];

  for (int k0 = 0; k0 < K; k0 += 32) {
    async16(ag + k0, asl);
    async16(ag + (size_t)16 * K + k0, asl + 16 * 32);
    async16(wg + k0, bsl);
    async16(wg + (size_t)16 * K + k0, bsl + 16 * 32);
    __syncthreads();   // drains vmcnt (global_load_lds) before LDS reads
    const bf16* ap = &As[(((wave >> 1) * 64) + lr) * 32 + quad * 8];
    const bf16* bp = &Bs[(((wave & 1) * 64) + lr) * 32 + quad * 8];
    bf16x8 af[4], bfr[4];
#pragma unroll
    for (int i = 0; i < 4; ++i) af[i] = *(const bf16x8*)(ap + i * 16 * 32);
#pragma unroll
    for (int j = 0; j < 4; ++j) bfr[j] = *(const bf16x8*)(bp + j * 16 * 32);
#pragma unroll
    for (int i = 0; i < 4; ++i)
#pragma unroll
      for (int j = 0; j < 4; ++j)
        acc[i][j] = __builtin_amdgcn_mfma_f32_16x16x32_bf16(af[i], bfr[j], acc[i][j], 0, 0, 0);
    __syncthreads();   // protect LDS from next iteration's staging
  }

  // Epilogue. D layout (verified m89/m91): col = lane&15, row = quad*4 + reg.
  const size_t mbase = arow + (wave >> 1) * 64;
  const size_t nbase = brow + (wave & 1) * 64;
#pragma unroll
  for (int i = 0; i < 4; ++i)
#pragma unroll
    for (int j = 0; j < 4; ++j)
#pragma unroll
      for (int r = 0; r < 4; ++r) {
        size_t m = mbase + i * 16 + quad * 4 + r;
        size_t n = nbase + j * 16 + lr;
        float v = acc[i][j][r];
        if (EPI == 0) {
          if (n < DM) {
            size_t idx = m * DM + n;
            out_f[idx] = v;
            out_b[idx] = (bf16)v;
          } else {
            out_f2[m * DM + (n - DM)] = v;
          }
        } else if (EPI == 1) {
          float tt = v + aux[n];
          float sp = (tt > 0.f) ? tt + log1pf(__expf(-tt)) : log1pf(__expf(tt));
          out_f[m * DM + n] = sp;
        } else {
          out_f[m * DM + n] = v + aux[m * DM + n];
        }
      }
}

// ---------------------------------------------------------------------------
// B_t / C_t projections (N=16 each, K=1024) in f32. One block per token row.
// ---------------------------------------------------------------------------
__global__ void bc_kernel(const float* __restrict__ x_in, const float* __restrict__ W_B,
                          const float* __restrict__ W_C, float* __restrict__ B_t,
                          float* __restrict__ C_t) {
  const size_t row = blockIdx.x;
  __shared__ float xs[DM];
  ((float4*)xs)[threadIdx.x] = ((const float4*)(x_in + row * DM))[threadIdx.x];
  __syncthreads();
  int wave = threadIdx.x >> 6, lane = threadIdx.x & 63;
#pragma unroll
  for (int jj = 0; jj < 8; ++jj) {
    int j = wave * 8 + jj;  // 0..31; waves 0,1 -> B, waves 2,3 -> C (uniform)
    const float* w = (j < NS) ? (W_B + (size_t)j * DM) : (W_C + (size_t)(j - NS) * DM);
    float p = 0.f;
#pragma unroll
    for (int i = 0; i < 16; ++i) p += xs[lane + i * 64] * w[lane + i * 64];
#pragma unroll
    for (int m = 1; m < 64; m <<= 1) p += __shfl_xor(p, m, 64);
    if (lane == 0) {
      if (j < NS) B_t[row * NS + j] = p;
      else        C_t[row * NS + (j - NS)] = p;
    }
  }
}

// ---------------------------------------------------------------------------
// Selective scan. Block = 256 threads = one batch b, 16 d-channels; thread
// (dl,n) owns state h[b, d0+dl, n]. Chunked (32 timesteps) LDS staging.
// ---------------------------------------------------------------------------
__global__ void scan_kernel(const float* __restrict__ dt, const float* __restrict__ x_in,
                            const float* __restrict__ B_t, const float* __restrict__ C_t,
                            const float* __restrict__ A_log, const float* __restrict__ h_prev,
                            float* __restrict__ y, float* __restrict__ h_final) {
  const int blk = blockIdx.x;        // 512 blocks
  const int b = blk >> 6;            // 64 d-blocks per batch
  const int d0 = (blk & 63) * 16;
  const int t = threadIdx.x;
  const int n = t & 15, dl = t >> 4;
  const int d = d0 + dl;
  const float Ac = -__expf(A_log[d * NS + n]);
  float h = h_prev[(size_t)b * DM * NS + (size_t)d * NS + n];

  __shared__ float dt_s[32][16], xi_s[32][16], Bsh[32][16], Csh[32][16], ys[32][16];
  const size_t base_row = (size_t)b * LSEQ;

  for (int l0 = 0; l0 < LSEQ; l0 += 32) {
#pragma unroll
    for (int e = t; e < 512; e += 256) {
      int l = e >> 4, dc = e & 15;
      size_t gidx = (base_row + l0 + l) * DM + d0 + dc;
      dt_s[l][dc] = dt[gidx];
      xi_s[l][dc] = x_in[gidx];
      ((float*)Bsh)[e] = B_t[(base_row + l0) * NS + e];
      ((float*)Csh)[e] = C_t[(base_row + l0) * NS + e];
    }
    __syncthreads();
#pragma unroll 4
    for (int l = 0; l < 32; ++l) {
      float dtv = dt_s[l][dl];
      float a = __expf(dtv * Ac);
      h = a * h + (dtv * xi_s[l][dl]) * Bsh[l][n];
      float p = h * Csh[l][n];
      p += __shfl_xor(p, 1); p += __shfl_xor(p, 2);
      p += __shfl_xor(p, 4); p += __shfl_xor(p, 8);
      if (n == 0) ys[l][dl] = p;
    }
    __syncthreads();
#pragma unroll
    for (int e = t; e < 512; e += 256) {
      int l = e >> 4, dc = e & 15;
      y[(base_row + l0 + l) * DM + d0 + dc] = ys[l][dc];
    }
    __syncthreads();
  }
  // h_final[b, d, n]; t == dl*16+n maps exactly to (d0+dl)*16+n ordering
  h_final[(size_t)b * DM * NS + (size_t)d0 * NS + t] = h;
}

// ---------------------------------------------------------------------------
// ssm_out = y * silu(z) + x_in * D  -> bf16 (for final GEMM). float4 lanes.
// ---------------------------------------------------------------------------
__global__ void ssm_elem(const float* __restrict__ y, const float* __restrict__ z,
                         const float* __restrict__ xi, const float* __restrict__ Dv,
                         bf16* __restrict__ out) {
  size_t i = (size_t)blockIdx.x * 256 + threadIdx.x;   // 2M float4 groups
  float4 yv = ((const float4*)y)[i];
  float4 zv = ((const float4*)z)[i];
  float4 xv = ((const float4*)xi)[i];
  int dbase = (int)((i * 4) & (DM - 1));
  float4 dv = *(const float4*)(Dv + dbase);
  bf16x4 o;
  o.x = (bf16)(yv.x * (zv.x / (1.f + __expf(-zv.x))) + xv.x * dv.x);
  o.y = (bf16)(yv.y * (zv.y / (1.f + __expf(-zv.y))) + xv.y * dv.y);
  o.z = (bf16)(yv.z * (zv.z / (1.f + __expf(-zv.z))) + xv.z * dv.z);
  o.w = (bf16)(yv.w * (zv.w / (1.f + __expf(-zv.w))) + xv.w * dv.w);
  *(bf16x4*)(out + 4 * i) = o;
}

// ---------------------------------------------------------------------------
extern "C" void kernel_launch(void* const* d_in, const int* in_sizes, int n_in,
                              void* d_out, int out_size, void* d_ws, size_t ws_size,
                              hipStream_t stream) {
  const float* x      = (const float*)d_in[0];
  const float* h_prev = (const float*)d_in[1];
  const float* ln_g   = (const float*)d_in[2];
  const float* ln_b   = (const float*)d_in[3];
  const float* W_ig   = (const float*)d_in[4];
  const float* W_dt   = (const float*)d_in[5];
  const float* b_dt   = (const float*)d_in[6];
  const float* A_log  = (const float*)d_in[7];
  const float* W_B    = (const float*)d_in[8];
  const float* W_C    = (const float*)d_in[9];
  const float* Dvec   = (const float*)d_in[10];
  const float* W_out  = (const float*)d_in[11];

  // Workspace carve-up (~194 MB total)
  char* ws = (char*)d_ws;
  size_t off = 0;
  auto alloc = [&](size_t bytes) -> char* {
    char* p = ws + off;
    off += (bytes + 255) & ~(size_t)255;
    return p;
  };
  bf16*  xnorm_b = (bf16*)alloc((size_t)MROWS * DM * 2);      // 16 MB
  bf16*  wig_b   = (bf16*)alloc((size_t)2 * DM * DM * 2);     // 4 MB
  bf16*  wdt_b   = (bf16*)alloc((size_t)DM * DM * 2);         // 2 MB
  bf16*  wout_b  = (bf16*)alloc((size_t)DM * DM * 2);         // 2 MB
  float* xin_f   = (float*)alloc((size_t)MROWS * DM * 4);     // 32 MB
  bf16*  xin_b   = (bf16*)alloc((size_t)MROWS * DM * 2);      // 16 MB
  float* z_f     = (float*)alloc((size_t)MROWS * DM * 4);     // 32 MB
  float* dt_f    = (float*)alloc((size_t)MROWS * DM * 4);     // 32 MB
  float* y_f     = (float*)alloc((size_t)MROWS * DM * 4);     // 32 MB
  bf16*  ssm_b   = (bf16*)alloc((size_t)MROWS * DM * 2);      // 16 MB
  float* Bt      = (float*)alloc((size_t)MROWS * NS * 4);     // 0.5 MB
  float* Ct      = (float*)alloc((size_t)MROWS * NS * 4);     // 0.5 MB
  (void)ws_size; (void)in_sizes; (void)n_in; (void)out_size;

  float* out_main = (float*)d_out;
  float* out_h    = (float*)d_out + (size_t)MROWS * DM;

  // 1) weight casts to bf16
  cast_f2b<<<(2 * DM * DM / 4 + 255) / 256, 256, 0, stream>>>(W_ig, wig_b, 2 * DM * DM / 4);
  cast_f2b<<<(DM * DM / 4 + 255) / 256, 256, 0, stream>>>(W_dt, wdt_b, DM * DM / 4);
  cast_f2b<<<(DM * DM / 4 + 255) / 256, 256, 0, stream>>>(W_out, wout_b, DM * DM / 4);

  // 2) layernorm -> bf16
  ln_kernel<<<MROWS, 256, 0, stream>>>(x, ln_g, ln_b, xnorm_b);

  // 3) x_proj GEMM (M=8192, N=2048, K=1024): split x_in / z
  gemm_bf16<0><<<dim3(16, 64), 256, 0, stream>>>(xnorm_b, wig_b, DM, xin_f, xin_b, z_f, nullptr);

  // 4) B_t / C_t from f32 x_in
  bc_kernel<<<MROWS, 256, 0, stream>>>(xin_f, W_B, W_C, Bt, Ct);

  // 5) dt GEMM (M=8192, N=1024, K=1024) + softplus
  gemm_bf16<1><<<dim3(8, 64), 256, 0, stream>>>(xin_b, wdt_b, DM, dt_f, nullptr, nullptr, b_dt);

  // 6) selective scan -> y, h_final
  scan_kernel<<<512, 256, 0, stream>>>(dt_f, xin_f, Bt, Ct, A_log, h_prev, y_f, out_h);

  // 7) ssm_out = y*silu(z) + x_in*D -> bf16
  ssm_elem<<<MROWS * DM / 4 / 256, 256, 0, stream>>>(y_f, z_f, xin_f, Dvec, ssm_b);

  // 8) output GEMM (M=8192, N=1024, K=1024) + residual x
  gemm_bf16<2><<<dim3(8, 64), 256, 0, stream>>>(ssm_b, wout_b, DM, out_main, nullptr, nullptr, x);
}

// Round 2
// 461.146 us; speedup vs baseline: 1.3265x; 1.3265x over previous
//
#include <hip/hip_runtime.h>
#include <hip/hip_bf16.h>
#include <math.h>

// Problem constants (fixed by setup_inputs)
#define DM 1024          // d_model
#define NS 16            // d_state
#define BSZ 8
#define LSEQ 1024
#define MROWS (BSZ*LSEQ) // 8192 token rows
#define CH 32            // scan chunk (timesteps staged per LDS buffer)

typedef __bf16 bf16;
typedef bf16 bf16x8 __attribute__((ext_vector_type(8)));
typedef bf16 bf16x4 __attribute__((ext_vector_type(4)));
typedef float f32x4 __attribute__((ext_vector_type(4)));

__device__ __forceinline__ void async16(const void* g, void* l) {
  __builtin_amdgcn_global_load_lds((const __attribute__((address_space(1))) void*)g,
                                   (__attribute__((address_space(3))) void*)l,
                                   16, 0, 0);
}

// DPP row_ror add: p += lanes rotated by R within 16-lane row (VALU pipe, no LDS)
template <int CTRL>
__device__ __forceinline__ float dpp_add(float v) {
  int x = __builtin_amdgcn_update_dpp(0, __builtin_bit_cast(int, v), CTRL, 0xf, 0xf, true);
  return v + __builtin_bit_cast(float, x);
}
__device__ __forceinline__ float row_reduce16(float p) {
  p = dpp_add<0x121>(p);  // row_ror:1
  p = dpp_add<0x122>(p);  // row_ror:2
  p = dpp_add<0x124>(p);  // row_ror:4
  p = dpp_add<0x128>(p);  // row_ror:8
  return p;               // all 16 lanes hold the row sum
}

// ---------------------------------------------------------------------------
// f32 -> bf16 cast (weights)
// ---------------------------------------------------------------------------
__global__ void cast_f2b(const float* __restrict__ s, bf16* __restrict__ d, int n4) {
  int i = blockIdx.x * 256 + threadIdx.x;
  if (i < n4) {
    float4 v = ((const float4*)s)[i];
    bf16x4 o;
    o.x = (bf16)v.x; o.y = (bf16)v.y; o.z = (bf16)v.z; o.w = (bf16)v.w;
    *(bf16x4*)(d + 4 * (size_t)i) = o;
  }
}

// ---------------------------------------------------------------------------
// LayerNorm over d=1024, writes bf16 x_norm. One block (256 thr) per row.
// ---------------------------------------------------------------------------
__global__ void ln_kernel(const float* __restrict__ x, const float* __restrict__ g,
                          const float* __restrict__ b, bf16* __restrict__ out) {
  const size_t row = blockIdx.x;
  const int t = threadIdx.x;
  float4 v = ((const float4*)(x + row * DM))[t];
  float s = v.x + v.y + v.z + v.w;
  float s2 = v.x*v.x + v.y*v.y + v.z*v.z + v.w*v.w;
#pragma unroll
  for (int m = 1; m < 64; m <<= 1) { s += __shfl_xor(s, m, 64); s2 += __shfl_xor(s2, m, 64); }
  __shared__ float red[8];
  int wave = t >> 6, lane = t & 63;
  if (lane == 0) { red[wave] = s; red[4 + wave] = s2; }
  __syncthreads();
  s  = red[0] + red[1] + red[2] + red[3];
  s2 = red[4] + red[5] + red[6] + red[7];
  float mu  = s * (1.f / DM);
  float var = s2 * (1.f / DM) - mu * mu;
  float inv = rsqrtf(var + 1e-5f);
  float4 gg = ((const float4*)g)[t];
  float4 bb = ((const float4*)b)[t];
  bf16x4 o;
  o.x = (bf16)((v.x - mu) * inv * gg.x + bb.x);
  o.y = (bf16)((v.y - mu) * inv * gg.y + bb.y);
  o.z = (bf16)((v.z - mu) * inv * gg.z + bb.z);
  o.w = (bf16)((v.w - mu) * inv * gg.w + bb.w);
  *(bf16x4*)(out + row * DM + t * 4) = o;
}

// ---------------------------------------------------------------------------
// MFMA bf16 GEMM: C[M,N] = A[M,K] @ W[N,K]^T  (m97 structure: 128x128 tile,
// BK=32, 4 waves -> 2x2 grid of 64x64 wave tiles, 4x4 MFMA 16x16x32 per wave,
// global_load_lds width=16 staging).
// EPI 0: split into x_in(f32 + bf16) [n<1024] and z(f32) [n>=1024]
// EPI 1: n<1024: dt = softplus(acc + b_dt[n]); 1024<=n<1040: B_t;
//        1040<=n<1056: C_t; else discard (weight rows there are garbage)
// EPI 2: out = acc + residual[m*DM+n]
// ---------------------------------------------------------------------------
template <int EPI>
__global__ __launch_bounds__(256)
void gemm_bf16(const bf16* __restrict__ A, const bf16* __restrict__ W, int K,
               float* __restrict__ out_f, bf16* __restrict__ out_b,
               float* __restrict__ out_f2, const float* __restrict__ aux,
               float* __restrict__ out_f3) {
  __shared__ bf16 As[128 * 32];
  __shared__ bf16 Bs[128 * 32];
  const int tid  = threadIdx.x;
  const int wave = tid >> 6, lane = tid & 63;
  const int lr = lane & 15, quad = lane >> 4;
  const size_t arow = (size_t)blockIdx.y * 128;
  const size_t brow = (size_t)blockIdx.x * 128;
  f32x4 acc[4][4] = {};

  const int srow = wave * 32 + (lane >> 2);
  const int skc  = (lane & 3) * 8;
  const bf16* ag = A + (arow + srow) * (size_t)K + skc;
  const bf16* wg = W + (brow + srow) * (size_t)K + skc;
  bf16* asl = &As[wave * 32 * 32];
  bf16* bsl = &Bs[wave * 32 * 32];

  for (int k0 = 0; k0 < K; k0 += 32) {
    async16(ag + k0, asl);
    async16(ag + (size_t)16 * K + k0, asl + 16 * 32);
    async16(wg + k0, bsl);
    async16(wg + (size_t)16 * K + k0, bsl + 16 * 32);
    __syncthreads();
    const bf16* ap = &As[(((wave >> 1) * 64) + lr) * 32 + quad * 8];
    const bf16* bp = &Bs[(((wave & 1) * 64) + lr) * 32 + quad * 8];
    bf16x8 af[4], bfr[4];
#pragma unroll
    for (int i = 0; i < 4; ++i) af[i] = *(const bf16x8*)(ap + i * 16 * 32);
#pragma unroll
    for (int j = 0; j < 4; ++j) bfr[j] = *(const bf16x8*)(bp + j * 16 * 32);
#pragma unroll
    for (int i = 0; i < 4; ++i)
#pragma unroll
      for (int j = 0; j < 4; ++j)
        acc[i][j] = __builtin_amdgcn_mfma_f32_16x16x32_bf16(af[i], bfr[j], acc[i][j], 0, 0, 0);
    __syncthreads();
  }

  // Epilogue. D layout (verified m89/m91): col = lane&15, row = quad*4 + reg.
  const size_t mbase = arow + (wave >> 1) * 64;
  const size_t nbase = brow + (wave & 1) * 64;
#pragma unroll
  for (int i = 0; i < 4; ++i)
#pragma unroll
    for (int j = 0; j < 4; ++j)
#pragma unroll
      for (int r = 0; r < 4; ++r) {
        size_t m = mbase + i * 16 + quad * 4 + r;
        size_t n = nbase + j * 16 + lr;
        float v = acc[i][j][r];
        if (EPI == 0) {
          if (n < DM) {
            size_t idx = m * DM + n;
            out_f[idx] = v;
            out_b[idx] = (bf16)v;
          } else {
            out_f2[m * DM + (n - DM)] = v;
          }
        } else if (EPI == 1) {
          if (n < DM) {
            float tt = v + aux[n];
            float sp = (tt > 0.f) ? tt + log1pf(__expf(-tt)) : log1pf(__expf(tt));
            out_f[m * DM + n] = sp;
          } else if (n < DM + NS) {
            out_f2[m * NS + (n - DM)] = v;          // B_t
          } else if (n < DM + 2 * NS) {
            out_f3[m * NS + (n - DM - NS)] = v;     // C_t
          } // else: garbage weight rows, discard
        } else {
          out_f[m * DM + n] = v + aux[m * DM + n];
        }
      }
}

// ---------------------------------------------------------------------------
// Selective scan. Block = one (batch b, 16 d-channels); thread (dl,n) owns
// h[b, d0+dl, n]. LDS-pipe minimized: interleaved float2 (dt,xi)/(B,C) reads
// via ds_read_b64, DPP row_ror reduction (VALU, zero LDS), double-buffered
// 32-step chunks with register prefetch of the next chunk.
// ---------------------------------------------------------------------------
__global__ __launch_bounds__(256)
void scan_kernel(const float* __restrict__ dt, const float* __restrict__ x_in,
                 const float* __restrict__ B_t, const float* __restrict__ C_t,
                 const float* __restrict__ A_log, const float* __restrict__ h_prev,
                 float* __restrict__ y, float* __restrict__ h_final) {
  const int blk = blockIdx.x;        // 512 blocks
  const int b = blk >> 6;
  const int d0 = (blk & 63) * 16;
  const int t = threadIdx.x;
  const int n = t & 15, dl = t >> 4;
  const int d = d0 + dl;
  // fold log2(e) into A so the step is a single v_exp_f32 (exp2)
  const float Ac2 = -__expf(A_log[d * NS + n]) * 1.44269504f;
  float h = h_prev[(size_t)b * DM * NS + (size_t)d * NS + n];

  __shared__ float2 dxs[2][CH][16];  // (dt, xi) per (l, dl)
  __shared__ float2 bcs[2][CH][16];  // (B, C)  per (l, n)
  __shared__ float  ys[CH][16];

  const size_t base_row = (size_t)b * LSEQ;
  // staging indices: element e in [0,512) -> l = e>>4, c16 = e&15 ; e = t, t+256
  const int l_a = t >> 4,  c_a = t & 15;        // e = t
  const int l_b = l_a + 16, c_b = c_a;          // e = t + 256

  // --- stage chunk 0 ---
  {
    size_t ga = (base_row + l_a) * DM + d0 + c_a;
    size_t gb = (base_row + l_b) * DM + d0 + c_b;
    dxs[0][l_a][c_a] = make_float2(dt[ga], x_in[ga]);
    dxs[0][l_b][c_b] = make_float2(dt[gb], x_in[gb]);
    size_t gB = base_row * NS;
    bcs[0][l_a][c_a] = make_float2(B_t[gB + t],       C_t[gB + t]);
    bcs[0][l_b][c_b] = make_float2(B_t[gB + t + 256], C_t[gB + t + 256]);
  }
  __syncthreads();

  for (int c = 0; c < LSEQ / CH; ++c) {
    const int cur = c & 1, nxt = cur ^ 1;
    // prefetch next chunk into registers (overlaps the compute below)
    float2 pdxa, pdxb, pbca, pbcb;
    if (c + 1 < LSEQ / CH) {
      size_t l0 = (size_t)(c + 1) * CH;
      size_t ga = (base_row + l0 + l_a) * DM + d0 + c_a;
      size_t gb = (base_row + l0 + l_b) * DM + d0 + c_b;
      pdxa = make_float2(dt[ga], x_in[ga]);
      pdxb = make_float2(dt[gb], x_in[gb]);
      size_t gB = (base_row + l0) * NS;
      pbca = make_float2(B_t[gB + t],       C_t[gB + t]);
      pbcb = make_float2(B_t[gB + t + 256], C_t[gB + t + 256]);
    }
#pragma unroll
    for (int l = 0; l < CH; ++l) {
      float2 dx = dxs[cur][l][dl];   // broadcast over 16 n-lanes
      float2 bc = bcs[cur][l][n];
      float a = __builtin_amdgcn_exp2f(dx.x * Ac2);
      h = fmaf(a, h, (dx.x * dx.y) * bc.x);
      float p = row_reduce16(h * bc.y);
      if (n == 0) ys[l][dl] = p;
    }
    __syncthreads();
    // write y for this chunk (coalesced)
    {
      size_t l0 = (size_t)c * CH;
      y[(base_row + l0 + l_a) * DM + d0 + c_a] = ys[l_a][c_a];
      y[(base_row + l0 + l_b) * DM + d0 + c_b] = ys[l_b][c_b];
    }
    if (c + 1 < LSEQ / CH) {
      dxs[nxt][l_a][c_a] = pdxa;
      dxs[nxt][l_b][c_b] = pdxb;
      bcs[nxt][l_a][c_a] = pbca;
      bcs[nxt][l_b][c_b] = pbcb;
    }
    __syncthreads();
  }
  h_final[(size_t)b * DM * NS + (size_t)d0 * NS + t] = h;
}

// ---------------------------------------------------------------------------
// ssm_out = y * silu(z) + x_in * D  -> bf16 (for final GEMM). float4 lanes.
// ---------------------------------------------------------------------------
__global__ void ssm_elem(const float* __restrict__ y, const float* __restrict__ z,
                         const float* __restrict__ xi, const float* __restrict__ Dv,
                         bf16* __restrict__ out) {
  size_t i = (size_t)blockIdx.x * 256 + threadIdx.x;
  float4 yv = ((const float4*)y)[i];
  float4 zv = ((const float4*)z)[i];
  float4 xv = ((const float4*)xi)[i];
  int dbase = (int)((i * 4) & (DM - 1));
  float4 dv = *(const float4*)(Dv + dbase);
  bf16x4 o;
  o.x = (bf16)(yv.x * (zv.x / (1.f + __expf(-zv.x))) + xv.x * dv.x);
  o.y = (bf16)(yv.y * (zv.y / (1.f + __expf(-zv.y))) + xv.y * dv.y);
  o.z = (bf16)(yv.z * (zv.z / (1.f + __expf(-zv.z))) + xv.z * dv.z);
  o.w = (bf16)(yv.w * (zv.w / (1.f + __expf(-zv.w))) + xv.w * dv.w);
  *(bf16x4*)(out + 4 * i) = o;
}

// ---------------------------------------------------------------------------
extern "C" void kernel_launch(void* const* d_in, const int* in_sizes, int n_in,
                              void* d_out, int out_size, void* d_ws, size_t ws_size,
                              hipStream_t stream) {
  const float* x      = (const float*)d_in[0];
  const float* h_prev = (const float*)d_in[1];
  const float* ln_g   = (const float*)d_in[2];
  const float* ln_b   = (const float*)d_in[3];
  const float* W_ig   = (const float*)d_in[4];
  const float* W_dt   = (const float*)d_in[5];
  const float* b_dt   = (const float*)d_in[6];
  const float* A_log  = (const float*)d_in[7];
  const float* W_B    = (const float*)d_in[8];
  const float* W_C    = (const float*)d_in[9];
  const float* Dvec   = (const float*)d_in[10];
  const float* W_out  = (const float*)d_in[11];

  char* ws = (char*)d_ws;
  size_t off = 0;
  auto alloc = [&](size_t bytes) -> char* {
    char* p = ws + off;
    off += (bytes + 255) & ~(size_t)255;
    return p;
  };
  bf16*  xnorm_b = (bf16*)alloc((size_t)MROWS * DM * 2);      // 16 MB
  bf16*  wig_b   = (bf16*)alloc((size_t)2 * DM * DM * 2);     // 4 MB
  bf16*  wdtbc_b = (bf16*)alloc((size_t)1152 * DM * 2);       // 2.25 MB (W_dt|W_B|W_C|garbage)
  bf16*  wout_b  = (bf16*)alloc((size_t)DM * DM * 2);         // 2 MB
  float* xin_f   = (float*)alloc((size_t)MROWS * DM * 4);     // 32 MB
  bf16*  xin_b   = (bf16*)alloc((size_t)MROWS * DM * 2);      // 16 MB
  float* z_f     = (float*)alloc((size_t)MROWS * DM * 4);     // 32 MB
  float* dt_f    = (float*)alloc((size_t)MROWS * DM * 4);     // 32 MB
  float* y_f     = (float*)alloc((size_t)MROWS * DM * 4);     // 32 MB
  bf16*  ssm_b   = (bf16*)alloc((size_t)MROWS * DM * 2);      // 16 MB
  float* Bt      = (float*)alloc((size_t)MROWS * NS * 4);     // 0.5 MB
  float* Ct      = (float*)alloc((size_t)MROWS * NS * 4);     // 0.5 MB
  (void)ws_size; (void)in_sizes; (void)n_in; (void)out_size;

  float* out_main = (float*)d_out;
  float* out_h    = (float*)d_out + (size_t)MROWS * DM;

  // 1) weight casts to bf16 (W_dt/W_B/W_C stacked into one 1056-row matrix;
  //    rows 1056-1151 stay poison — their GEMM outputs are discarded)
  cast_f2b<<<(2 * DM * DM / 4 + 255) / 256, 256, 0, stream>>>(W_ig, wig_b, 2 * DM * DM / 4);
  cast_f2b<<<(DM * DM / 4 + 255) / 256, 256, 0, stream>>>(W_dt, wdtbc_b, DM * DM / 4);
  cast_f2b<<<(NS * DM / 4 + 255) / 256, 256, 0, stream>>>(W_B, wdtbc_b + (size_t)DM * DM, NS * DM / 4);
  cast_f2b<<<(NS * DM / 4 + 255) / 256, 256, 0, stream>>>(W_C, wdtbc_b + (size_t)(DM + NS) * DM, NS * DM / 4);
  cast_f2b<<<(DM * DM / 4 + 255) / 256, 256, 0, stream>>>(W_out, wout_b, DM * DM / 4);

  // 2) layernorm -> bf16
  ln_kernel<<<MROWS, 256, 0, stream>>>(x, ln_g, ln_b, xnorm_b);

  // 3) x_proj GEMM (M=8192, N=2048, K=1024): split x_in / z
  gemm_bf16<0><<<dim3(16, 64), 256, 0, stream>>>(xnorm_b, wig_b, DM, xin_f, xin_b, z_f, nullptr, nullptr);

  // 4) dt GEMM (M=8192, N=1152, K=1024): softplus dt + B_t + C_t fused
  gemm_bf16<1><<<dim3(9, 64), 256, 0, stream>>>(xin_b, wdtbc_b, DM, dt_f, nullptr, Bt, b_dt, Ct);

  // 5) selective scan -> y, h_final
  scan_kernel<<<512, 256, 0, stream>>>(dt_f, xin_f, Bt, Ct, A_log, h_prev, y_f, out_h);

  // 6) ssm_out = y*silu(z) + x_in*D -> bf16
  ssm_elem<<<MROWS * DM / 4 / 256, 256, 0, stream>>>(y_f, z_f, xin_f, Dvec, ssm_b);

  // 7) output GEMM (M=8192, N=1024, K=1024) + residual x
  gemm_bf16<2><<<dim3(8, 64), 256, 0, stream>>>(ssm_b, wout_b, DM, out_main, nullptr, nullptr, x, nullptr);
}

// Round 3
// 395.416 us; speedup vs baseline: 1.5470x; 1.1662x over previous
//
#include <hip/hip_runtime.h>
#include <hip/hip_bf16.h>
#include <math.h>

// Problem constants (fixed by setup_inputs)
#define DM 1024          // d_model
#define NS 16            // d_state
#define BSZ 8
#define LSEQ 1024
#define MROWS (BSZ*LSEQ) // 8192 token rows
#define CH 32            // scan chunk (timesteps staged per LDS buffer)
#define NMEGA 3104       // x_in(1024) + z(1024) + dt(1024) + B(16) + C(16)

typedef __bf16 bf16;
typedef bf16 bf16x8 __attribute__((ext_vector_type(8)));
typedef bf16 bf16x4 __attribute__((ext_vector_type(4)));
typedef float f32x4 __attribute__((ext_vector_type(4)));

__device__ __forceinline__ void async16(const void* g, void* l) {
  __builtin_amdgcn_global_load_lds((const __attribute__((address_space(1))) void*)g,
                                   (__attribute__((address_space(3))) void*)l,
                                   16, 0, 0);
}

// DPP row_ror add chain: 16-lane row reduction on the VALU pipe (no LDS traffic)
template <int CTRL>
__device__ __forceinline__ float dpp_add(float v) {
  int x = __builtin_amdgcn_update_dpp(0, __builtin_bit_cast(int, v), CTRL, 0xf, 0xf, true);
  return v + __builtin_bit_cast(float, x);
}
__device__ __forceinline__ float row_reduce16(float p) {
  p = dpp_add<0x121>(p);
  p = dpp_add<0x122>(p);
  p = dpp_add<0x124>(p);
  p = dpp_add<0x128>(p);
  return p;
}

// ---------------------------------------------------------------------------
// f32 -> bf16 cast (weights)
// ---------------------------------------------------------------------------
__global__ void cast_f2b(const float* __restrict__ s, bf16* __restrict__ d, int n4) {
  int i = blockIdx.x * 256 + threadIdx.x;
  if (i < n4) {
    float4 v = ((const float4*)s)[i];
    bf16x4 o;
    o.x = (bf16)v.x; o.y = (bf16)v.y; o.z = (bf16)v.z; o.w = (bf16)v.w;
    *(bf16x4*)(d + 4 * (size_t)i) = o;
  }
}

// ---------------------------------------------------------------------------
// Transpose + cast: dst[k][d] = (bf16) src[d][k], 1024x1024. 64x64 LDS tiles.
// ---------------------------------------------------------------------------
__global__ void transpose_cast(const float* __restrict__ src, bf16* __restrict__ dst) {
  __shared__ float tile[64][65];
  const int bk = blockIdx.x * 64;   // k-tile
  const int bd = blockIdx.y * 64;   // d-tile
  const int t = threadIdx.x;
  const int c4 = t & 15;            // 16 float4 col-groups
  const int r0 = t >> 4;            // 16 rows per pass
#pragma unroll
  for (int p = 0; p < 4; ++p) {
    int r = r0 + p * 16;
    float4 v = *(const float4*)(src + (size_t)(bd + r) * 1024 + bk + c4 * 4);
    tile[r][c4 * 4 + 0] = v.x;
    tile[r][c4 * 4 + 1] = v.y;
    tile[r][c4 * 4 + 2] = v.z;
    tile[r][c4 * 4 + 3] = v.w;
  }
  __syncthreads();
#pragma unroll
  for (int p = 0; p < 4; ++p) {
    int r = r0 + p * 16;            // k-local
    bf16x4 o;
    o.x = (bf16)tile[c4 * 4 + 0][r];
    o.y = (bf16)tile[c4 * 4 + 1][r];
    o.z = (bf16)tile[c4 * 4 + 2][r];
    o.w = (bf16)tile[c4 * 4 + 3][r];
    *(bf16x4*)(dst + (size_t)(bk + r) * 1024 + bd + c4 * 4) = o;
  }
}

// ---------------------------------------------------------------------------
// LayerNorm over d=1024, writes bf16 x_norm. One block (256 thr) per row.
// ---------------------------------------------------------------------------
__global__ void ln_kernel(const float* __restrict__ x, const float* __restrict__ g,
                          const float* __restrict__ b, bf16* __restrict__ out) {
  const size_t row = blockIdx.x;
  const int t = threadIdx.x;
  float4 v = ((const float4*)(x + row * DM))[t];
  float s = v.x + v.y + v.z + v.w;
  float s2 = v.x*v.x + v.y*v.y + v.z*v.z + v.w*v.w;
#pragma unroll
  for (int m = 1; m < 64; m <<= 1) { s += __shfl_xor(s, m, 64); s2 += __shfl_xor(s2, m, 64); }
  __shared__ float red[8];
  int wave = t >> 6, lane = t & 63;
  if (lane == 0) { red[wave] = s; red[4 + wave] = s2; }
  __syncthreads();
  s  = red[0] + red[1] + red[2] + red[3];
  s2 = red[4] + red[5] + red[6] + red[7];
  float mu  = s * (1.f / DM);
  float var = s2 * (1.f / DM) - mu * mu;
  float inv = rsqrtf(var + 1e-5f);
  float4 gg = ((const float4*)g)[t];
  float4 bb = ((const float4*)b)[t];
  bf16x4 o;
  o.x = (bf16)((v.x - mu) * inv * gg.x + bb.x);
  o.y = (bf16)((v.y - mu) * inv * gg.y + bb.y);
  o.z = (bf16)((v.z - mu) * inv * gg.z + bb.z);
  o.w = (bf16)((v.w - mu) * inv * gg.w + bb.w);
  *(bf16x4*)(out + row * DM + t * 4) = o;
}

// ---------------------------------------------------------------------------
// MFMA bf16 GEMM: C[M,N] = A[M,K] @ W[N,K]^T. 128x128 tile, BK=64 as two
// m97-style 32-wide sub-stages per barrier pair (halves barrier drains vs
// BK=32). 4 waves -> 2x2 grid of 64x64 wave tiles, 4x4 MFMA 16x16x32 each.
// EPI 0 (mega): n<1024 -> x_in f32; <2048 -> z bf16; <3072 -> softplus dt f32;
//               <3088 -> B_t; <3104 -> C_t; else discard.
// EPI 2: out = acc + residual[m*DM+n]
// EPI 3 (compose): out_b[m*1024+n] = bf16(acc)
// ---------------------------------------------------------------------------
template <int EPI>
__global__ __launch_bounds__(256)
void gemm_bf16(const bf16* __restrict__ A, const bf16* __restrict__ W, int K,
               float* __restrict__ out_f, bf16* __restrict__ out_b,
               float* __restrict__ out_f2, const float* __restrict__ aux,
               float* __restrict__ out_f3, float* __restrict__ out_f4) {
  __shared__ bf16 As[2][128 * 32];
  __shared__ bf16 Bs[2][128 * 32];
  const int tid  = threadIdx.x;
  const int wave = tid >> 6, lane = tid & 63;
  const int lr = lane & 15, quad = lane >> 4;
  const size_t arow = (size_t)blockIdx.y * 128;
  const size_t brow = (size_t)blockIdx.x * 128;
  f32x4 acc[4][4] = {};

  const int srow = wave * 32 + (lane >> 2);
  const int skc  = (lane & 3) * 8;
  const bf16* ag = A + (arow + srow) * (size_t)K + skc;
  const bf16* wg = W + (brow + srow) * (size_t)K + skc;
  bf16* asl0 = &As[0][wave * 32 * 32];
  bf16* asl1 = &As[1][wave * 32 * 32];
  bf16* bsl0 = &Bs[0][wave * 32 * 32];
  bf16* bsl1 = &Bs[1][wave * 32 * 32];

  for (int k0 = 0; k0 < K; k0 += 64) {
    async16(ag + k0,                     asl0);
    async16(ag + (size_t)16 * K + k0,    asl0 + 16 * 32);
    async16(ag + k0 + 32,                asl1);
    async16(ag + (size_t)16 * K + k0 + 32, asl1 + 16 * 32);
    async16(wg + k0,                     bsl0);
    async16(wg + (size_t)16 * K + k0,    bsl0 + 16 * 32);
    async16(wg + k0 + 32,                bsl1);
    async16(wg + (size_t)16 * K + k0 + 32, bsl1 + 16 * 32);
    __syncthreads();
#pragma unroll
    for (int kh = 0; kh < 2; ++kh) {
      const bf16* ap = &As[kh][(((wave >> 1) * 64) + lr) * 32 + quad * 8];
      const bf16* bp = &Bs[kh][(((wave & 1) * 64) + lr) * 32 + quad * 8];
      bf16x8 af[4], bfr[4];
#pragma unroll
      for (int i = 0; i < 4; ++i) af[i] = *(const bf16x8*)(ap + i * 16 * 32);
#pragma unroll
      for (int j = 0; j < 4; ++j) bfr[j] = *(const bf16x8*)(bp + j * 16 * 32);
#pragma unroll
      for (int i = 0; i < 4; ++i)
#pragma unroll
        for (int j = 0; j < 4; ++j)
          acc[i][j] = __builtin_amdgcn_mfma_f32_16x16x32_bf16(af[i], bfr[j], acc[i][j], 0, 0, 0);
    }
    __syncthreads();
  }

  // Epilogue. D layout (verified m89/m91): col = lane&15, row = quad*4 + reg.
  const size_t mbase = arow + (wave >> 1) * 64;
  const size_t nbase = brow + (wave & 1) * 64;
#pragma unroll
  for (int i = 0; i < 4; ++i)
#pragma unroll
    for (int j = 0; j < 4; ++j)
#pragma unroll
      for (int r = 0; r < 4; ++r) {
        size_t m = mbase + i * 16 + quad * 4 + r;
        size_t n = nbase + j * 16 + lr;
        float v = acc[i][j][r];
        if (EPI == 0) {
          if (n < DM) {
            out_f[m * DM + n] = v;                       // x_in f32
          } else if (n < 2 * DM) {
            out_b[m * DM + (n - DM)] = (bf16)v;          // z bf16
          } else if (n < 3 * DM) {
            float tt = v + aux[n - 2 * DM];
            float sp = (tt > 20.f) ? tt : __logf(1.f + __expf(tt));
            out_f2[m * DM + (n - 2 * DM)] = sp;          // dt f32
          } else if (n < 3 * DM + NS) {
            out_f3[m * NS + (n - 3 * DM)] = v;           // B_t
          } else if (n < 3 * DM + 2 * NS) {
            out_f4[m * NS + (n - 3 * DM - NS)] = v;      // C_t
          } // else: garbage columns, discard
        } else if (EPI == 2) {
          out_f[m * DM + n] = v + aux[m * DM + n];
        } else if (EPI == 3) {
          out_b[m * (size_t)DM + n] = (bf16)v;           // composed weight rows
        }
      }
}

// ---------------------------------------------------------------------------
// Selective scan + fused output gate. Block = (batch b, 16 d-channels);
// thread (dl,n) owns h[b, d0+dl, n]. DPP reduction, double-buffered chunks,
// writes ssm_out = y*silu(z) + x_in*D directly as bf16.
// ---------------------------------------------------------------------------
__global__ __launch_bounds__(256)
void scan_kernel(const float* __restrict__ dt, const float* __restrict__ x_in,
                 const bf16* __restrict__ z_b,
                 const float* __restrict__ B_t, const float* __restrict__ C_t,
                 const float* __restrict__ A_log, const float* __restrict__ h_prev,
                 const float* __restrict__ Dvec,
                 bf16* __restrict__ ssm_out, float* __restrict__ h_final) {
  const int blk = blockIdx.x;        // 512 blocks
  const int b = blk >> 6;
  const int d0 = (blk & 63) * 16;
  const int t = threadIdx.x;
  const int n = t & 15, dl = t >> 4;
  const int d = d0 + dl;
  const float Ac2 = -__expf(A_log[d * NS + n]) * 1.44269504f;  // fold log2e
  float h = h_prev[(size_t)b * DM * NS + (size_t)d * NS + n];

  __shared__ float2 dxs[2][CH][16];  // (dt, xi) per (l, dl)
  __shared__ float2 bcs[2][CH][16];  // (B, C)  per (l, n)
  __shared__ float  ys[CH][16];

  const size_t base_row = (size_t)b * LSEQ;
  const int l_a = t >> 4,  c_a = t & 15;        // staging element t
  const int l_b = l_a + 16, c_b = c_a;          // staging element t+256
  const float Dva = Dvec[d0 + c_a];

  float za, zb;
  {
    size_t ga = (base_row + l_a) * DM + d0 + c_a;
    size_t gb = (base_row + l_b) * DM + d0 + c_b;
    dxs[0][l_a][c_a] = make_float2(dt[ga], x_in[ga]);
    dxs[0][l_b][c_b] = make_float2(dt[gb], x_in[gb]);
    za = (float)z_b[ga]; zb = (float)z_b[gb];
    size_t gB = base_row * NS;
    bcs[0][l_a][c_a] = make_float2(B_t[gB + t],       C_t[gB + t]);
    bcs[0][l_b][c_b] = make_float2(B_t[gB + t + 256], C_t[gB + t + 256]);
  }
  __syncthreads();

  for (int c = 0; c < LSEQ / CH; ++c) {
    const int cur = c & 1, nxt = cur ^ 1;
    float2 pdxa, pdxb, pbca, pbcb; float pza, pzb;
    if (c + 1 < LSEQ / CH) {
      size_t l0 = (size_t)(c + 1) * CH;
      size_t ga = (base_row + l0 + l_a) * DM + d0 + c_a;
      size_t gb = (base_row + l0 + l_b) * DM + d0 + c_b;
      pdxa = make_float2(dt[ga], x_in[ga]);
      pdxb = make_float2(dt[gb], x_in[gb]);
      pza = (float)z_b[ga]; pzb = (float)z_b[gb];
      size_t gB = (base_row + l0) * NS;
      pbca = make_float2(B_t[gB + t],       C_t[gB + t]);
      pbcb = make_float2(B_t[gB + t + 256], C_t[gB + t + 256]);
    }
#pragma unroll
    for (int l = 0; l < CH; ++l) {
      float2 dx = dxs[cur][l][dl];
      float2 bc = bcs[cur][l][n];
      float a = __builtin_amdgcn_exp2f(dx.x * Ac2);
      h = fmaf(a, h, (dx.x * dx.y) * bc.x);
      float p = row_reduce16(h * bc.y);
      if (n == 0) ys[l][dl] = p;
    }
    __syncthreads();
    {
      size_t l0 = (size_t)c * CH;
      float xa = dxs[cur][l_a][c_a].y;
      float xb = dxs[cur][l_b][c_b].y;
      float sa = za / (1.f + __expf(-za));
      float sb = zb / (1.f + __expf(-zb));
      ssm_out[(base_row + l0 + l_a) * DM + d0 + c_a] = (bf16)(ys[l_a][c_a] * sa + xa * Dva);
      ssm_out[(base_row + l0 + l_b) * DM + d0 + c_b] = (bf16)(ys[l_b][c_b] * sb + xb * Dva);
    }
    if (c + 1 < LSEQ / CH) {
      dxs[nxt][l_a][c_a] = pdxa;
      dxs[nxt][l_b][c_b] = pdxb;
      bcs[nxt][l_a][c_a] = pbca;
      bcs[nxt][l_b][c_b] = pbcb;
      za = pza; zb = pzb;
    }
    __syncthreads();
  }
  h_final[(size_t)b * DM * NS + (size_t)d0 * NS + t] = h;
}

// ---------------------------------------------------------------------------
extern "C" void kernel_launch(void* const* d_in, const int* in_sizes, int n_in,
                              void* d_out, int out_size, void* d_ws, size_t ws_size,
                              hipStream_t stream) {
  const float* x      = (const float*)d_in[0];
  const float* h_prev = (const float*)d_in[1];
  const float* ln_g   = (const float*)d_in[2];
  const float* ln_b   = (const float*)d_in[3];
  const float* W_ig   = (const float*)d_in[4];
  const float* W_dt   = (const float*)d_in[5];
  const float* b_dt   = (const float*)d_in[6];
  const float* A_log  = (const float*)d_in[7];
  const float* W_B    = (const float*)d_in[8];
  const float* W_C    = (const float*)d_in[9];
  const float* Dvec   = (const float*)d_in[10];
  const float* W_out  = (const float*)d_in[11];

  char* ws = (char*)d_ws;
  size_t off = 0;
  auto alloc = [&](size_t bytes) -> char* {
    char* p = ws + off;
    off += (bytes + 255) & ~(size_t)255;
    return p;
  };
  // Combined mega weight: rows 0-2047 = W_ig, 2048-3103 = composed dt/B/C,
  // 3104-3199 = garbage pad (outputs discarded).
  bf16*  wmega_b = (bf16*)alloc((size_t)3200 * DM * 2);       // 6.25 MB
  bf16*  wstack_b= (bf16*)alloc((size_t)1152 * DM * 2);       // 2.25 MB (Wdt|WB|WC|pad)
  bf16*  wigT_b  = (bf16*)alloc((size_t)DM * DM * 2);         // 2 MB (W_ig[:1024]^T)
  bf16*  wout_b  = (bf16*)alloc((size_t)DM * DM * 2);         // 2 MB
  bf16*  xnorm_b = (bf16*)alloc((size_t)MROWS * DM * 2);      // 16 MB
  float* xin_f   = (float*)alloc((size_t)MROWS * DM * 4);     // 32 MB
  bf16*  z_bb    = (bf16*)alloc((size_t)MROWS * DM * 2);      // 16 MB
  float* dt_f    = (float*)alloc((size_t)MROWS * DM * 4);     // 32 MB
  bf16*  ssm_b   = (bf16*)alloc((size_t)MROWS * DM * 2);      // 16 MB
  float* Bt      = (float*)alloc((size_t)MROWS * NS * 4);     // 0.5 MB
  float* Ct      = (float*)alloc((size_t)MROWS * NS * 4);     // 0.5 MB
  (void)ws_size; (void)in_sizes; (void)n_in; (void)out_size;

  float* out_main = (float*)d_out;
  float* out_h    = (float*)d_out + (size_t)MROWS * DM;

  // 1) weight casts
  cast_f2b<<<(2 * DM * DM / 4 + 255) / 256, 256, 0, stream>>>(W_ig, wmega_b, 2 * DM * DM / 4);
  cast_f2b<<<(DM * DM / 4 + 255) / 256, 256, 0, stream>>>(W_dt, wstack_b, DM * DM / 4);
  cast_f2b<<<(NS * DM / 4 + 255) / 256, 256, 0, stream>>>(W_B, wstack_b + (size_t)DM * DM, NS * DM / 4);
  cast_f2b<<<(NS * DM / 4 + 255) / 256, 256, 0, stream>>>(W_C, wstack_b + (size_t)(DM + NS) * DM, NS * DM / 4);
  cast_f2b<<<(DM * DM / 4 + 255) / 256, 256, 0, stream>>>(W_out, wout_b, DM * DM / 4);
  // 2) W_ig[:1024]^T (for weight composition)
  transpose_cast<<<dim3(16, 16), 256, 0, stream>>>(W_ig, wigT_b);

  // 3) layernorm -> bf16
  ln_kernel<<<MROWS, 256, 0, stream>>>(x, ln_g, ln_b, xnorm_b);

  // 4) compose: wmega[2048+e][k] = sum_d [Wdt;WB;WC][e][d] * W_ig[d][k]
  gemm_bf16<3><<<dim3(8, 9), 256, 0, stream>>>(wstack_b, wigT_b, DM,
      nullptr, wmega_b + (size_t)2048 * DM, nullptr, nullptr, nullptr, nullptr);

  // 5) mega GEMM (M=8192, N=3104(pad 3200), K=1024): x_in, z, dt, B_t, C_t
  gemm_bf16<0><<<dim3(25, 64), 256, 0, stream>>>(xnorm_b, wmega_b, DM,
      xin_f, z_bb, dt_f, b_dt, Bt, Ct);

  // 6) selective scan + fused gate -> ssm_b, h_final
  scan_kernel<<<512, 256, 0, stream>>>(dt_f, xin_f, z_bb, Bt, Ct, A_log, h_prev,
                                       Dvec, ssm_b, out_h);

  // 7) output GEMM (M=8192, N=1024, K=1024) + residual x
  gemm_bf16<2><<<dim3(8, 64), 256, 0, stream>>>(ssm_b, wout_b, DM,
      out_main, nullptr, nullptr, x, nullptr, nullptr);
}